// Round 8
// baseline (172.428 us; speedup 1.0000x reference)
//
#include <hip/hip_runtime.h>
#include <stdint.h>

// Flash-attention fwd, causal, GQA (H=16, Hkv=8), B=2, S=2048, D=128, fp32 io.
// Round 12: barrier-free main loop - K/V read DIRECTLY from the pre-swizzled
// global tile images (L2-resident), no LDS staging at all.
//  * r11 post-mortem: two barrier domains = flat (62us) -> stall is the
//    per-wave serial chain + lockstep barriers, not the drain itself.
//  * The LDS copy was byte-identity (lsKV[y] = ktiles[kt*8192+y]), so each
//    ds_read_b128 becomes global_load_dwordx4 at the same swizzled offset:
//    no barriers, no DMA writes, no ds_reads, no bank conflicts. Waves
//    free-run through their 33 iters.
//  * Latency hidden within the wave: V(t) loads issued at iter start
//    (covered by QK+softmax); K(t+1) prefetched into 32 VGPRs right after
//    QK(t) consumes kpre (covered by softmax+PV+V(t+1)). VGPR ~210 fits the
//    256 cap at (256,2) - r10's spill was its (512,2)=128 cap.
//  * L2 locality: all 16 blocks of a (b,head) pair sit on one XCD
//    (bx mod 8 = rem mod 8); plane = 1MB; load traffic ~1.08GB ~ 57% of L2
//    ceiling at 55us.
//  * Grid/balance/epilogue = proven r11 (512 blocks x 4 waves, sequential
//    (p,31-p) pair, 33 iters/block); epilogue scratch = dedicated 33KB LDS.

#define SQ 2048
#define SK 2048
#define NH 16
#define NKV 8
#define DH 128
#define KVSTRIDE (2*NKV*DH)       // 2048 floats between consecutive s in kv
#define SCALE_LOG2E 0.12751743f   // (1/sqrt(128)) * log2(e)

typedef __attribute__((ext_vector_type(8))) short bf8;   // 8 x bf16 (4 VGPR)
typedef __attribute__((ext_vector_type(4))) float f4;
typedef __attribute__((ext_vector_type(4))) int i4;

__device__ __forceinline__ float fast_exp2(float x) {
  return __builtin_amdgcn_exp2f(x);        // v_exp_f32: 2^x
}

__device__ __forceinline__ short f2bf(float f) {
  uint32_t u = __builtin_bit_cast(uint32_t, f);
  u += 0x7FFFu + ((u >> 16) & 1u);          // RNE
  return (short)(u >> 16);
}

__device__ __forceinline__ int cvtpk(float lo, float hi) {
  int r;
  asm("v_cvt_pk_bf16_f32 %0, %1, %2" : "=v"(r) : "v"(lo), "v"(hi));
  return r;                                  // [15:0]=bf16(lo) [31:16]=bf16(hi)
}

__device__ __forceinline__ bf8 pack8(f4 a, f4 b) {
  bf8 v;
  v[0] = f2bf(a[0]); v[1] = f2bf(a[1]); v[2] = f2bf(a[2]); v[3] = f2bf(a[3]);
  v[4] = f2bf(b[0]); v[5] = f2bf(b[1]); v[6] = f2bf(b[2]); v[7] = f2bf(b[3]);
  return v;
}
__device__ __forceinline__ bf8 pack8s(f4 a, f4 b, float s) {
  bf8 v;
  v[0] = f2bf(a[0]*s); v[1] = f2bf(a[1]*s); v[2] = f2bf(a[2]*s); v[3] = f2bf(a[3]*s);
  v[4] = f2bf(b[0]*s); v[5] = f2bf(b[1]*s); v[6] = f2bf(b[2]*s); v[7] = f2bf(b[3]*s);
  return v;
}

template<int CTRL>
__device__ __forceinline__ float dppmov(float x) {
  int xi = __builtin_bit_cast(int, x);
  int r = __builtin_amdgcn_update_dpp(xi, xi, CTRL, 0xF, 0xF, false);
  return __builtin_bit_cast(float, r);
}
__device__ __forceinline__ float rowsum16(float v) {   // row_ror 1/2/4/8
  v += dppmov<0x121>(v);
  v += dppmov<0x122>(v);
  v += dppmov<0x124>(v);
  v += dppmov<0x128>(v);
  return v;
}
__device__ __forceinline__ float rowmax16(float v) {
  v = fmaxf(v, dppmov<0x121>(v));
  v = fmaxf(v, dppmov<0x122>(v));
  v = fmaxf(v, dppmov<0x124>(v));
  v = fmaxf(v, dppmov<0x128>(v));
  return v;
}

// ---------------- pre-pass: kv fp32 -> bf16 swizzled tile images ------------
// Kb tile (b,hk,kt): 64x128, PERMUTED rows: physical key p stored at row
//   a(p) = (p&0x23) | ((p&4)<<2) | ((p&0x18)>>1)   (bits p5,p2,p4,p3,p1,p0)
//   chunk(row,c) at (row*16 + (c^(row&7)))*8 shorts.
// Vb tile (b,hk,kt): transposed 128x64 (physical key order),
//   chunk(d,c) at (d*8 + (c^(d&7)))*8
__global__ void conv_kv(const float* __restrict__ kv,
                        short* __restrict__ Kb, short* __restrict__ Vb) {
  int id = blockIdx.x * 256 + threadIdx.x;     // 524288 per plane
  if (blockIdx.y == 0) {
    int c   = id & 15;
    int key = (id >> 4) & 63;                  // physical key
    int kt  = (id >> 10) & 31;
    int hk  = (id >> 15) & 7;
    int b   = (id >> 18) & 1;
    const float* src = kv + ((size_t)(b * SK + kt * 64 + key) * 2) * (NKV * DH)
                          + hk * DH + c * 8;
    f4 a = *(const f4*)src;
    f4 bb = *(const f4*)(src + 4);
    short* dst = Kb + ((size_t)((b * 8 + hk) * 32 + kt)) * 8192;
    int akey = (key & 0x23) | ((key & 4) << 2) | ((key & 0x18) >> 1);
    *(bf8*)&dst[(akey * 16 + (c ^ (akey & 7))) * 8] = pack8(a, bb);
  } else {
    int d  = id & 127;
    int c  = (id >> 7) & 7;
    int kt = (id >> 10) & 31;
    int hk = (id >> 15) & 7;
    int b  = (id >> 18) & 1;
    const float* src = kv + ((size_t)(b * SK + kt * 64 + c * 8) * 2 + 1) * (NKV * DH)
                          + hk * DH + d;
    bf8 v;
#pragma unroll
    for (int kk = 0; kk < 8; ++kk) v[kk] = f2bf(src[(size_t)kk * KVSTRIDE]);
    short* dst = Vb + ((size_t)((b * 8 + hk) * 32 + kt)) * 8192;
    *(bf8*)&dst[(d * 8 + (c ^ (d & 7))) * 8] = v;
  }
}

// -- main kernel: barrier-free loop, global K/V, key-split mt=2, in-reg P ---
__launch_bounds__(256, 2)
__global__ void fa_fwd10(const float* __restrict__ q,
                         const short* __restrict__ Kb,
                         const short* __restrict__ Vb,
                         float* __restrict__ out) {
  __shared__ __align__(16) float lsO[2][4096];   // 32 KB epilogue O-scratch
  __shared__ float lsL[256];                     //  1 KB l-scratch

  const int tid  = threadIdx.x;
  const int w    = tid >> 6;           // 4 waves
  const int l    = tid & 63;
  const int l15  = l & 15;
  const int quad = l >> 4;

  const int bx   = blockIdx.x;
  const int p    = bx >> 5;            // 0..15 -> tile pair (p, 31-p)
  const int rem  = bx & 31;
  const int b    = rem >> 4;
  const int head = rem & 15;
  const int hk   = head >> 1;

  const int h     = w >> 1;            // key half (0: keys 0-31, 1: 32-63)
  const int mrow0 = (w & 1) * 32;      // row half

  const short* ktiles = Kb + ((size_t)((b * 8 + hk) * 32)) * 8192;
  const short* vtiles = Vb + ((size_t)((b * 8 + hk) * 32)) * 8192;

#pragma unroll 1
  for (int phase = 0; phase < 2; ++phase) {
    const int qt = phase ? (31 - p) : p;
    const int q0 = qt * 64;

    // ---- Q fragments (B-operand of swapped QK^T; col = l15 = q-row) ----
    bf8 qf[2][4];
#pragma unroll
    for (int mt = 0; mt < 2; ++mt) {
      int row = q0 + mrow0 + mt * 16 + l15;
      const float* qr = q + ((size_t)(b * SQ + row) * NH + head) * DH;
#pragma unroll
      for (int kc = 0; kc < 4; ++kc) {
        const float* src = qr + kc * 32 + quad * 8;
        f4 a = *(const f4*)src;
        f4 c = *(const f4*)(src + 4);
        qf[mt][kc] = pack8s(a, c, SCALE_LOG2E);
      }
    }

    f4 O[2][8];
#pragma unroll
    for (int mt = 0; mt < 2; ++mt)
#pragma unroll
      for (int nt = 0; nt < 8; ++nt) O[mt][nt] = (f4){0.f, 0.f, 0.f, 0.f};
    float lpart[2] = {0.f, 0.f};       // lane's q-rows: mrow0+mt*16+l15

    // ---- prologue: K(0) fragments -> registers ----
    bf8 kpre[4][2];
#pragma unroll
    for (int kc = 0; kc < 4; ++kc)
#pragma unroll
      for (int nt = 0; nt < 2; ++nt) {
        int row = h * 32 + nt * 16 + l15;   // Kb row (permuted slot)
        int c   = kc * 4 + quad;
        kpre[kc][nt] = *(const bf8*)&ktiles[(row * 16 + (c ^ (row & 7))) * 8];
      }

#pragma unroll 1
    for (int kt = 0; kt <= qt; ++kt) {
      // ---- V(t) loads issued first (consumed at PV, ~800 cyc later) ----
      const short* vt = vtiles + (size_t)kt * 8192;
      bf8 vf[8];
#pragma unroll
      for (int nt = 0; nt < 8; ++nt) {
        int d = nt * 16 + l15;
        int c = h * 4 + quad;
        vf[nt] = *(const bf8*)&vt[(d * 8 + (c ^ (d & 7))) * 8];
      }

      // ---- S^T = K Q^T from kpre (16 MFMAs; kf reused x2) ----
      f4 S[2][2];
#pragma unroll
      for (int mt = 0; mt < 2; ++mt)
#pragma unroll
        for (int nt = 0; nt < 2; ++nt) S[mt][nt] = (f4){0.f, 0.f, 0.f, 0.f};
      __builtin_amdgcn_s_setprio(1);
#pragma unroll
      for (int kc = 0; kc < 4; ++kc) {
#pragma unroll
        for (int nt = 0; nt < 2; ++nt) {
          S[0][nt] = __builtin_amdgcn_mfma_f32_16x16x32_bf16(kpre[kc][nt], qf[0][kc], S[0][nt], 0, 0, 0);
          S[1][nt] = __builtin_amdgcn_mfma_f32_16x16x32_bf16(kpre[kc][nt], qf[1][kc], S[1][nt], 0, 0, 0);
        }
      }
      __builtin_amdgcn_s_setprio(0);

      // ---- prefetch K(t+1) into kpre (consumed next iter) ----
      if (kt < qt) {
        const short* kt1 = ktiles + (size_t)(kt + 1) * 8192;
#pragma unroll
        for (int kc = 0; kc < 4; ++kc)
#pragma unroll
          for (int nt = 0; nt < 2; ++nt) {
            int row = h * 32 + nt * 16 + l15;
            int c   = kc * 4 + quad;
            kpre[kc][nt] = *(const bf8*)&kt1[(row * 16 + (c ^ (row & 7))) * 8];
          }
      }

      if (kt == qt) {                  // diagonal: causal mask (physical key)
#pragma unroll
        for (int mt = 0; mt < 2; ++mt)
#pragma unroll
          for (int nt = 0; nt < 2; ++nt)
#pragma unroll
            for (int r = 0; r < 4; ++r) {
              int kphys = h * 32 + (quad << 3) + (nt << 2) + r;
              if (kphys > mrow0 + mt * 16 + l15) S[mt][nt][r] = -1e30f;
            }
      }

      // ---- fixed-ref softmax, fully in-register ----
#pragma unroll
      for (int mt = 0; mt < 2; ++mt)
#pragma unroll
        for (int nt = 0; nt < 2; ++nt)
#pragma unroll
          for (int r = 0; r < 4; ++r) {
            float pe = fast_exp2(S[mt][nt][r]);
            S[mt][nt][r] = pe;
            lpart[mt] += pe;
          }

      // ---- P -> PV A-fragments (lane-local; element j=4nt+r) ----
      bf8 pf[2];
#pragma unroll
      for (int mt = 0; mt < 2; ++mt) {
        i4 wv;
        wv[0] = cvtpk(S[mt][0][0], S[mt][0][1]);
        wv[1] = cvtpk(S[mt][0][2], S[mt][0][3]);
        wv[2] = cvtpk(S[mt][1][0], S[mt][1][1]);
        wv[3] = cvtpk(S[mt][1][2], S[mt][1][3]);
        pf[mt] = __builtin_bit_cast(bf8, wv);
      }

      // ---- O += P V from vf registers (16 MFMAs) ----
      __builtin_amdgcn_s_setprio(1);
#pragma unroll
      for (int nt = 0; nt < 8; ++nt) {
        O[0][nt] = __builtin_amdgcn_mfma_f32_16x16x32_bf16(pf[0], vf[nt], O[0][nt], 0, 0, 0);
        O[1][nt] = __builtin_amdgcn_mfma_f32_16x16x32_bf16(pf[1], vf[nt], O[1][nt], 0, 0, 0);
      }
      __builtin_amdgcn_s_setprio(0);
    }

    // ---- epilogue: sum O/l across key-half pair (w, w+2), then write ----
    __syncthreads();                   // sync the free-running waves
    if (w >= 2) {
      int uw = w - 2;                  // = rowhalf of this wave
      float* base = lsO[uw] + (size_t)l * 64;
#pragma unroll
      for (int mt = 0; mt < 2; ++mt)
#pragma unroll
        for (int nt = 0; nt < 8; ++nt) {
          int tt   = mt * 8 + nt;
          int slot = (tt + l15) & 15;  // rotate -> conflict-free scatter
          *(f4*)(base + slot * 4) = O[mt][nt];
        }
      lsL[(uw * 64 + l) * 2 + 0] = lpart[0];
      lsL[(uw * 64 + l) * 2 + 1] = lpart[1];
    }
    __syncthreads();
    if (w < 2) {                       // w = rowhalf
      float* base = lsO[w] + (size_t)l * 64;
#pragma unroll
      for (int mt = 0; mt < 2; ++mt)
#pragma unroll
        for (int nt = 0; nt < 8; ++nt) {
          int tt   = mt * 8 + nt;
          int slot = (tt + l15) & 15;
          O[mt][nt] += *(const f4*)(base + slot * 4);
        }
      lpart[0] += lsL[(w * 64 + l) * 2 + 0];
      lpart[1] += lsL[(w * 64 + l) * 2 + 1];

#pragma unroll
      for (int mt = 0; mt < 2; ++mt) {
        float lsum = lpart[mt];
        lsum += __shfl_xor(lsum, 16);
        lsum += __shfl_xor(lsum, 32);  // lanes 0-15: full l for q-row l15
#pragma unroll
        for (int r = 0; r < 4; ++r) {
          float lr   = __shfl(lsum, quad * 4 + r);
          float linv = 1.0f / lr;
          int row = q0 + mrow0 + mt * 16 + quad * 4 + r;
          float* dst = out + ((size_t)(b * SQ + row) * NH + head) * DH + l15;
#pragma unroll
          for (int nt = 0; nt < 8; ++nt) dst[nt * 16] = O[mt][nt][r] * linv;
        }
      }
    }
  }
}

// ---------------- fallback (round-1 style, no workspace needed) -------------
__launch_bounds__(256, 2)
__global__ void fa_fwd_v1(const float* __restrict__ q,
                          const float* __restrict__ kv,
                          float* __restrict__ out) {
  __shared__ __align__(16) short lsK[64 * 128];
  __shared__ __align__(16) short lsV[128 * 64];
  __shared__ __align__(16) short lsP[4][32 * 64];

  const int tid  = threadIdx.x;
  const int w    = tid >> 6;
  const int l    = tid & 63;
  const int l15  = l & 15;
  const int quad = l >> 4;

  const int bx  = blockIdx.x;
  const int qt  = 31 - (bx >> 4);
  const int bhk = bx & 15;
  const int b   = bhk >> 3;
  const int hk  = bhk & 7;
  const int head  = hk * 2 + (w >> 1);
  const int mrow0 = (w & 1) * 32;
  const int q0    = qt * 64;

  const float* kbase = kv + (size_t)b * SK * KVSTRIDE + (size_t)hk * DH;
  const float* vbase = kbase + NKV * DH;

  bf8 qf[2][4];
#pragma unroll
  for (int mt = 0; mt < 2; ++mt)
#pragma unroll
    for (int kc = 0; kc < 4; ++kc) {
      int row = q0 + mrow0 + mt * 16 + l15;
      int d0  = kc * 32 + quad * 8;
      const float* src = q + ((size_t)(b * SQ + row) * NH + head) * DH + d0;
      f4 a = *(const f4*)src;
      f4 c = *(const f4*)(src + 4);
      qf[mt][kc] = pack8s(a, c, SCALE_LOG2E);
    }

  f4 O[2][8];
  float mrow[2][4], lrow[2][4];
#pragma unroll
  for (int mt = 0; mt < 2; ++mt) {
#pragma unroll
    for (int nt = 0; nt < 8; ++nt) O[mt][nt] = (f4){0.f, 0.f, 0.f, 0.f};
#pragma unroll
    for (int r = 0; r < 4; ++r) { mrow[mt][r] = -1e30f; lrow[mt][r] = 0.f; }
  }

  for (int kt = 0; kt <= qt; ++kt) {
    if (kt) __syncthreads();
    const int k0 = kt * 64;
#pragma unroll
    for (int i = 0; i < 4; ++i) {
      int id  = i * 256 + tid;
      int key = id >> 4;
      int c   = id & 15;
      const float* src = kbase + (size_t)(k0 + key) * KVSTRIDE + c * 8;
      f4 a = *(const f4*)src;
      f4 bb = *(const f4*)(src + 4);
      *(bf8*)&lsK[(key * 16 + (c ^ (key & 7))) * 8] = pack8(a, bb);
    }
#pragma unroll
    for (int i = 0; i < 4; ++i) {
      int u  = i * 4 + w;
      int kg = u >> 1;
      int d  = (u & 1) * 64 + l;
      const float* src = vbase + (size_t)(k0 + kg * 8) * KVSTRIDE + d;
      bf8 v;
#pragma unroll
      for (int kk = 0; kk < 8; ++kk) v[kk] = f2bf(src[(size_t)kk * KVSTRIDE]);
      *(bf8*)&lsV[(d * 8 + (kg ^ (d & 7))) * 8] = v;
    }
    __syncthreads();

    f4 S[2][4];
#pragma unroll
    for (int mt = 0; mt < 2; ++mt)
#pragma unroll
      for (int nt = 0; nt < 4; ++nt) S[mt][nt] = (f4){0.f, 0.f, 0.f, 0.f};
#pragma unroll
    for (int kc = 0; kc < 4; ++kc)
#pragma unroll
      for (int nt = 0; nt < 4; ++nt) {
        int key = nt * 16 + l15;
        int c   = kc * 4 + quad;
        bf8 kf = *(const bf8*)&lsK[(key * 16 + (c ^ (key & 7))) * 8];
        S[0][nt] = __builtin_amdgcn_mfma_f32_16x16x32_bf16(qf[0][kc], kf, S[0][nt], 0, 0, 0);
        S[1][nt] = __builtin_amdgcn_mfma_f32_16x16x32_bf16(qf[1][kc], kf, S[1][nt], 0, 0, 0);
      }

    if (kt == qt) {
#pragma unroll
      for (int mt = 0; mt < 2; ++mt)
#pragma unroll
        for (int nt = 0; nt < 4; ++nt)
#pragma unroll
          for (int r = 0; r < 4; ++r) {
            int rloc = mrow0 + mt * 16 + quad * 4 + r;
            int kloc = nt * 16 + l15;
            if (kloc > rloc) S[mt][nt][r] = -1e30f;
          }
    }

#pragma unroll
    for (int mt = 0; mt < 2; ++mt)
#pragma unroll
      for (int r = 0; r < 4; ++r) {
        float mx = fmaxf(fmaxf(S[mt][0][r], S[mt][1][r]),
                         fmaxf(S[mt][2][r], S[mt][3][r]));
        mx = rowmax16(mx);
        float mold = mrow[mt][r];
        float mnew = fmaxf(mold, mx);
        float alpha = fast_exp2(mold - mnew);
        mrow[mt][r] = mnew;
        float rs = 0.f;
#pragma unroll
        for (int nt = 0; nt < 4; ++nt) {
          float pe = fast_exp2(S[mt][nt][r] - mnew);
          S[mt][nt][r] = pe;
          rs += pe;
        }
        rs = rowsum16(rs);
        lrow[mt][r] = lrow[mt][r] * alpha + rs;
#pragma unroll
        for (int nt = 0; nt < 8; ++nt) O[mt][nt][r] *= alpha;
        int m = mt * 16 + quad * 4 + r;
#pragma unroll
        for (int nt = 0; nt < 4; ++nt) {
          int key = nt * 16 + l15;
          lsP[w][(m * 8 + ((key >> 3) ^ (m & 7))) * 8 + (key & 7)] =
              f2bf(S[mt][nt][r]);
        }
      }

#pragma unroll
    for (int kc = 0; kc < 2; ++kc) {
      bf8 pf[2];
#pragma unroll
      for (int mt = 0; mt < 2; ++mt) {
        int m = mt * 16 + l15;
        int c = kc * 4 + quad;
        pf[mt] = *(const bf8*)&lsP[w][(m * 8 + (c ^ (m & 7))) * 8];
      }
#pragma unroll
      for (int nt = 0; nt < 8; ++nt) {
        int d = nt * 16 + l15;
        int c = kc * 4 + quad;
        bf8 vf = *(const bf8*)&lsV[(d * 8 + (c ^ (d & 7))) * 8];
        O[0][nt] = __builtin_amdgcn_mfma_f32_16x16x32_bf16(pf[0], vf, O[0][nt], 0, 0, 0);
        O[1][nt] = __builtin_amdgcn_mfma_f32_16x16x32_bf16(pf[1], vf, O[1][nt], 0, 0, 0);
      }
    }
  }

#pragma unroll
  for (int mt = 0; mt < 2; ++mt)
#pragma unroll
    for (int r = 0; r < 4; ++r) {
      float linv = 1.0f / lrow[mt][r];
      int row = q0 + mrow0 + mt * 16 + quad * 4 + r;
      float* dst = out + ((size_t)(b * SQ + row) * NH + head) * DH + l15;
#pragma unroll
      for (int nt = 0; nt < 8; ++nt) dst[nt * 16] = O[mt][nt][r] * linv;
    }
}

extern "C" void kernel_launch(void* const* d_in, const int* in_sizes, int n_in,
                              void* d_out, int out_size, void* d_ws, size_t ws_size,
                              hipStream_t stream) {
  const float* q  = (const float*)d_in[0];
  const float* kv = (const float*)d_in[1];
  float* out      = (float*)d_out;
  (void)in_sizes; (void)n_in; (void)out_size;

  const size_t kb_elems = (size_t)2 * 8 * 32 * 8192;          // 4,194,304 shorts
  const size_t need = 2 * kb_elems * sizeof(short);            // 16 MB

  if (ws_size >= need) {
    short* Kb = (short*)d_ws;
    short* Vb = Kb + kb_elems;
    conv_kv<<<dim3(2048, 2), 256, 0, stream>>>(kv, Kb, Vb);
    fa_fwd10<<<dim3(512), dim3(256), 0, stream>>>(q, Kb, Vb, out);
  } else {
    fa_fwd_v1<<<dim3(512), dim3(256), 0, stream>>>(q, kv, out);
  }
}

// Round 10
// 147.433 us; speedup vs baseline: 1.1695x; 1.1695x over previous
//
#include <hip/hip_runtime.h>
#include <stdint.h>

// Flash-attention fwd, causal, GQA (H=16, Hkv=8), B=2, S=2048, D=128, fp32 io.
// Round 14: 128-key iterations (two contiguous 64-key sub-tiles per stage) on
// the PROVEN classic double-buffer skeleton. Halves barrier/drain count
// (33 -> 17 per block) while keeping the exact hazard structure that passed
// 5/5 rounds: stage(T+1)->buf^1 right after the single per-iter barrier.
//  * r13 post-mortem: single-buffer 2-barrier raced (absmax 0.42), same class
//    as r9's tri-buffer. Only the classic skeleton is trusted.
//  * r11 vs r8 (2 vs 1 barrier domains) was flat -> cost is stage/drain
//    FREQUENCY, not who waits. So: amortize each drain over 2x compute.
//  * Per wave-iter: S[2][4], 32 QK + 32 PV MFMAs, 16+16 b128 reads (ratio
//    0.5 kept). Even-qt blocks get one fully-masked half-sub-tile (~3%,
//    uniform across blocks -> balance preserved: NT(p)+NT(31-p)=17).
//  * LDS: K dbuf 2x32KB + V dbuf 2x32KB + 2KB lsL = 130KB -> 1 block/CU.
//    launch_bounds(512,1) -> VGPR cap 256, no spill (r10/r12 killer).
//  * Sub-tile algebra = verified r7/r8: slot perm -> PV A-frag nt=2*kc+hh;
//    diag mask formula unchanged; st>qt sub-tile -> S=-1e30 (exp->0).
//  * Epilogue: r8's (w,w+4) key-half reduction verbatim, scratch in lsA.

#define SQ 2048
#define SK 2048
#define NH 16
#define NKV 8
#define DH 128
#define KVSTRIDE (2*NKV*DH)       // 2048 floats between consecutive s in kv
#define SCALE_LOG2E 0.12751743f   // (1/sqrt(128)) * log2(e)

typedef __attribute__((ext_vector_type(8))) short bf8;   // 8 x bf16 (4 VGPR)
typedef __attribute__((ext_vector_type(4))) float f4;
typedef __attribute__((ext_vector_type(4))) int i4;

__device__ __forceinline__ float fast_exp2(float x) {
  return __builtin_amdgcn_exp2f(x);        // v_exp_f32: 2^x
}

__device__ __forceinline__ short f2bf(float f) {
  uint32_t u = __builtin_bit_cast(uint32_t, f);
  u += 0x7FFFu + ((u >> 16) & 1u);          // RNE
  return (short)(u >> 16);
}

__device__ __forceinline__ int cvtpk(float lo, float hi) {
  int r;
  asm("v_cvt_pk_bf16_f32 %0, %1, %2" : "=v"(r) : "v"(lo), "v"(hi));
  return r;                                  // [15:0]=bf16(lo) [31:16]=bf16(hi)
}

__device__ __forceinline__ bf8 pack8(f4 a, f4 b) {
  bf8 v;
  v[0] = f2bf(a[0]); v[1] = f2bf(a[1]); v[2] = f2bf(a[2]); v[3] = f2bf(a[3]);
  v[4] = f2bf(b[0]); v[5] = f2bf(b[1]); v[6] = f2bf(b[2]); v[7] = f2bf(b[3]);
  return v;
}
__device__ __forceinline__ bf8 pack8s(f4 a, f4 b, float s) {
  bf8 v;
  v[0] = f2bf(a[0]*s); v[1] = f2bf(a[1]*s); v[2] = f2bf(a[2]*s); v[3] = f2bf(a[3]*s);
  v[4] = f2bf(b[0]*s); v[5] = f2bf(b[1]*s); v[6] = f2bf(b[2]*s); v[7] = f2bf(b[3]*s);
  return v;
}

template<int CTRL>
__device__ __forceinline__ float dppmov(float x) {
  int xi = __builtin_bit_cast(int, x);
  int r = __builtin_amdgcn_update_dpp(xi, xi, CTRL, 0xF, 0xF, false);
  return __builtin_bit_cast(float, r);
}
__device__ __forceinline__ float rowsum16(float v) {   // row_ror 1/2/4/8
  v += dppmov<0x121>(v);
  v += dppmov<0x122>(v);
  v += dppmov<0x124>(v);
  v += dppmov<0x128>(v);
  return v;
}
__device__ __forceinline__ float rowmax16(float v) {
  v = fmaxf(v, dppmov<0x121>(v));
  v = fmaxf(v, dppmov<0x122>(v));
  v = fmaxf(v, dppmov<0x124>(v));
  v = fmaxf(v, dppmov<0x128>(v));
  return v;
}

// async 16B global->LDS (wave-uniform base + lane*16 contiguous dest)
__device__ __forceinline__ void g2l16(const short* g, short* l) {
  __builtin_amdgcn_global_load_lds(
      (const __attribute__((address_space(1))) uint32_t*)g,
      (__attribute__((address_space(3))) uint32_t*)l, 16, 0, 0);
}

// ---------------- pre-pass: kv fp32 -> bf16 swizzled tile images ------------
// Kb tile (b,hk,kt): 64x128, PERMUTED rows: physical key p stored at row
//   a(p) = (p&0x23) | ((p&4)<<2) | ((p&0x18)>>1)   (bits p5,p2,p4,p3,p1,p0)
//   chunk(row,c) at (row*16 + (c^(row&7)))*8 shorts.
// Vb tile (b,hk,kt): transposed 128x64 (physical key order),
//   chunk(d,c) at (d*8 + (c^(d&7)))*8
__global__ void conv_kv(const float* __restrict__ kv,
                        short* __restrict__ Kb, short* __restrict__ Vb) {
  int id = blockIdx.x * 256 + threadIdx.x;     // 524288 per plane
  if (blockIdx.y == 0) {
    int c   = id & 15;
    int key = (id >> 4) & 63;                  // physical key
    int kt  = (id >> 10) & 31;
    int hk  = (id >> 15) & 7;
    int b   = (id >> 18) & 1;
    const float* src = kv + ((size_t)(b * SK + kt * 64 + key) * 2) * (NKV * DH)
                          + hk * DH + c * 8;
    f4 a = *(const f4*)src;
    f4 bb = *(const f4*)(src + 4);
    short* dst = Kb + ((size_t)((b * 8 + hk) * 32 + kt)) * 8192;
    int akey = (key & 0x23) | ((key & 4) << 2) | ((key & 0x18) >> 1);
    *(bf8*)&dst[(akey * 16 + (c ^ (akey & 7))) * 8] = pack8(a, bb);
  } else {
    int d  = id & 127;
    int c  = (id >> 7) & 7;
    int kt = (id >> 10) & 31;
    int hk = (id >> 15) & 7;
    int b  = (id >> 18) & 1;
    const float* src = kv + ((size_t)(b * SK + kt * 64 + c * 8) * 2 + 1) * (NKV * DH)
                          + hk * DH + d;
    bf8 v;
#pragma unroll
    for (int kk = 0; kk < 8; ++kk) v[kk] = f2bf(src[(size_t)kk * KVSTRIDE]);
    short* dst = Vb + ((size_t)((b * 8 + hk) * 32 + kt)) * 8192;
    *(bf8*)&dst[(d * 8 + (c ^ (d & 7))) * 8] = v;
  }
}

// -- main kernel: 128-key iters, classic dbuf, key-split mt=2, in-reg P -----
__launch_bounds__(512, 1)
__global__ void fa_fwd12(const float* __restrict__ q,
                         const short* __restrict__ Kb,
                         const short* __restrict__ Vb,
                         float* __restrict__ out) {
  __shared__ __align__(16) short lsA[2][16384];  // K dbuf: 2 x (two sub-tiles)
  __shared__ __align__(16) short lsB[2][16384];  // V dbuf
  __shared__ float lsL[512];                     // 2 KB l-scratch
  // 130 KB -> 1 block/CU. Epilogue O-scratch reuses lsA (16384 floats).

  const int tid  = threadIdx.x;
  const int w    = tid >> 6;           // 8 waves
  const int l    = tid & 63;
  const int l15  = l & 15;
  const int quad = l >> 4;

  const int bx  = blockIdx.x;
  const int p   = bx >> 4;             // 0..15 -> tile pair (p, 31-p)
  const int bhk = bx & 15;
  const int b   = bhk >> 3;
  const int hk  = bhk & 7;

  const int h     = w >> 2;            // key half of the 128: sub-tile 2T+h
  const int head  = hk * 2 + (w & 1);
  const int mrow0 = ((w >> 1) & 1) * 32;

  const short* ktiles = Kb + ((size_t)((b * 8 + hk) * 32)) * 8192;
  const short* vtiles = Vb + ((size_t)((b * 8 + hk) * 32)) * 8192;

  // stage 128-key group T (sub-tiles 2T, 2T+1 = 32KB each of K,V) into buf nb
  auto stage = [&](int T, int nb) {
    const short* ks = ktiles + (size_t)(2 * T) * 8192 + tid * 8;
    const short* vs = vtiles + (size_t)(2 * T) * 8192 + tid * 8;
#pragma unroll
    for (int i = 0; i < 4; ++i) {
      g2l16(ks + i * 4096, &lsA[nb][i * 4096 + tid * 8]);
      g2l16(vs + i * 4096, &lsB[nb][i * 4096 + tid * 8]);
    }
  };

#pragma unroll 1
  for (int phase = 0; phase < 2; ++phase) {
    const int qt = phase ? (31 - p) : p;
    const int q0 = qt * 64;
    const int NT = qt >> 1;            // iterations T = 0..NT (128 keys each)

    // ---- Q fragments (B-operand of swapped QK^T; col = l15 = q-row) ----
    bf8 qf[2][4];
#pragma unroll
    for (int mt = 0; mt < 2; ++mt) {
      int row = q0 + mrow0 + mt * 16 + l15;
      const float* qr = q + ((size_t)(b * SQ + row) * NH + head) * DH;
#pragma unroll
      for (int kc = 0; kc < 4; ++kc) {
        const float* src = qr + kc * 32 + quad * 8;
        f4 a = *(const f4*)src;
        f4 c = *(const f4*)(src + 4);
        qf[mt][kc] = pack8s(a, c, SCALE_LOG2E);
      }
    }

    f4 O[2][8];
#pragma unroll
    for (int mt = 0; mt < 2; ++mt)
#pragma unroll
      for (int nt = 0; nt < 8; ++nt) O[mt][nt] = (f4){0.f, 0.f, 0.f, 0.f};
    float lpart[2] = {0.f, 0.f};       // lane's q-rows: mrow0+mt*16+l15

    if (phase) __syncthreads();        // phase-A scratch readers done
    stage(0, 0);

#pragma unroll 1
    for (int T = 0; T <= NT; ++T) {
      const int cur = T & 1;
      __syncthreads();                 // stage(T) landed + prev readers done
      if (T < NT) stage(T + 1, cur ^ 1);

      const short* Kc = &lsA[cur][h * 8192];   // this wave's sub-tile 2T+h
      const short* Vc = &lsB[cur][h * 8192];

      // ---- S^T = K Q^T: 16 reads, 32 MFMAs (kf reused x2) ----
      f4 S[2][4];
#pragma unroll
      for (int mt = 0; mt < 2; ++mt)
#pragma unroll
        for (int nt = 0; nt < 4; ++nt) S[mt][nt] = (f4){0.f, 0.f, 0.f, 0.f};
      __builtin_amdgcn_s_setprio(1);
#pragma unroll
      for (int kc = 0; kc < 4; ++kc) {
#pragma unroll
        for (int nt = 0; nt < 4; ++nt) {
          int row = nt * 16 + l15;     // permuted slot within sub-tile
          int c   = kc * 4 + quad;
          bf8 kf = *(const bf8*)&Kc[(row * 16 + (c ^ (row & 7))) * 8];
          S[0][nt] = __builtin_amdgcn_mfma_f32_16x16x32_bf16(kf, qf[0][kc], S[0][nt], 0, 0, 0);
          S[1][nt] = __builtin_amdgcn_mfma_f32_16x16x32_bf16(kf, qf[1][kc], S[1][nt], 0, 0, 0);
        }
      }
      __builtin_amdgcn_s_setprio(0);

      const int st = 2 * T + h;        // this wave's sub-tile index
      if (st >= qt) {
        if (st > qt) {                 // fully beyond diagonal (even-qt tail)
#pragma unroll
          for (int mt = 0; mt < 2; ++mt)
#pragma unroll
            for (int nt = 0; nt < 4; ++nt)
#pragma unroll
              for (int r = 0; r < 4; ++r) S[mt][nt][r] = -1e30f;
        } else {                       // diagonal sub-tile: causal mask
#pragma unroll
          for (int mt = 0; mt < 2; ++mt)
#pragma unroll
            for (int nt = 0; nt < 4; ++nt)
#pragma unroll
              for (int r = 0; r < 4; ++r) {
                int kphys = ((nt >> 1) << 5) + (quad << 3) + ((nt & 1) << 2) + r;
                if (kphys > mrow0 + mt * 16 + l15) S[mt][nt][r] = -1e30f;
              }
        }
      }

      // ---- fixed-ref softmax, fully in-register ----
#pragma unroll
      for (int mt = 0; mt < 2; ++mt)
#pragma unroll
        for (int nt = 0; nt < 4; ++nt)
#pragma unroll
          for (int r = 0; r < 4; ++r) {
            float pe = fast_exp2(S[mt][nt][r]);
            S[mt][nt][r] = pe;
            lpart[mt] += pe;
          }

      // ---- P -> PV A-fragments (lane-local; slot nt = 2*kc2 + hh) ----
      bf8 pf[2][2];
#pragma unroll
      for (int mt = 0; mt < 2; ++mt)
#pragma unroll
        for (int kc2 = 0; kc2 < 2; ++kc2) {
          i4 wv;
          wv[0] = cvtpk(S[mt][2*kc2][0],   S[mt][2*kc2][1]);
          wv[1] = cvtpk(S[mt][2*kc2][2],   S[mt][2*kc2][3]);
          wv[2] = cvtpk(S[mt][2*kc2+1][0], S[mt][2*kc2+1][1]);
          wv[3] = cvtpk(S[mt][2*kc2+1][2], S[mt][2*kc2+1][3]);
          pf[mt][kc2] = __builtin_bit_cast(bf8, wv);
        }

      // ---- O += P V: 16 reads, 32 MFMAs (vf reused x2) ----
      __builtin_amdgcn_s_setprio(1);
#pragma unroll
      for (int kc2 = 0; kc2 < 2; ++kc2) {
#pragma unroll
        for (int nt = 0; nt < 8; ++nt) {
          int d = nt * 16 + l15;
          int c = kc2 * 4 + quad;
          bf8 vf = *(const bf8*)&Vc[(d * 8 + (c ^ (d & 7))) * 8];
          O[0][nt] = __builtin_amdgcn_mfma_f32_16x16x32_bf16(pf[0][kc2], vf, O[0][nt], 0, 0, 0);
          O[1][nt] = __builtin_amdgcn_mfma_f32_16x16x32_bf16(pf[1][kc2], vf, O[1][nt], 0, 0, 0);
        }
      }
      __builtin_amdgcn_s_setprio(0);
    }

    // ---- epilogue: sum O/l across key-half pair (w, w+4), then write ----
    __syncthreads();                   // all PV reads of lsB done
    if (w >= 4) {
      int uw = w - 4;
      float* base = (float*)&lsA[0][0] + uw * 4096 + (size_t)l * 64;
#pragma unroll
      for (int mt = 0; mt < 2; ++mt)
#pragma unroll
        for (int nt = 0; nt < 8; ++nt) {
          int tt   = mt * 8 + nt;
          int slot = (tt + l15) & 15;  // rotate -> conflict-free scatter
          *(f4*)(base + slot * 4) = O[mt][nt];
        }
      lsL[(uw * 64 + l) * 2 + 0] = lpart[0];
      lsL[(uw * 64 + l) * 2 + 1] = lpart[1];
    }
    __syncthreads();
    if (w < 4) {
      float* base = (float*)&lsA[0][0] + w * 4096 + (size_t)l * 64;
#pragma unroll
      for (int mt = 0; mt < 2; ++mt)
#pragma unroll
        for (int nt = 0; nt < 8; ++nt) {
          int tt   = mt * 8 + nt;
          int slot = (tt + l15) & 15;
          O[mt][nt] += *(const f4*)(base + slot * 4);
        }
      lpart[0] += lsL[(w * 64 + l) * 2 + 0];
      lpart[1] += lsL[(w * 64 + l) * 2 + 1];

#pragma unroll
      for (int mt = 0; mt < 2; ++mt) {
        float lsum = lpart[mt];
        lsum += __shfl_xor(lsum, 16);
        lsum += __shfl_xor(lsum, 32);  // lanes 0-15: full l for q-row l15
#pragma unroll
        for (int r = 0; r < 4; ++r) {
          float lr   = __shfl(lsum, quad * 4 + r);
          float linv = 1.0f / lr;
          int row = q0 + mrow0 + mt * 16 + quad * 4 + r;
          float* dst = out + ((size_t)(b * SQ + row) * NH + head) * DH + l15;
#pragma unroll
          for (int nt = 0; nt < 8; ++nt) dst[nt * 16] = O[mt][nt][r] * linv;
        }
      }
    }
  }
}

// ---------------- fallback (round-1 style, no workspace needed) -------------
__launch_bounds__(256, 2)
__global__ void fa_fwd_v1(const float* __restrict__ q,
                          const float* __restrict__ kv,
                          float* __restrict__ out) {
  __shared__ __align__(16) short lsK[64 * 128];
  __shared__ __align__(16) short lsV[128 * 64];
  __shared__ __align__(16) short lsP[4][32 * 64];

  const int tid  = threadIdx.x;
  const int w    = tid >> 6;
  const int l    = tid & 63;
  const int l15  = l & 15;
  const int quad = l >> 4;

  const int bx  = blockIdx.x;
  const int qt  = 31 - (bx >> 4);
  const int bhk = bx & 15;
  const int b   = bhk >> 3;
  const int hk  = bhk & 7;
  const int head  = hk * 2 + (w >> 1);
  const int mrow0 = (w & 1) * 32;
  const int q0    = qt * 64;

  const float* kbase = kv + (size_t)b * SK * KVSTRIDE + (size_t)hk * DH;
  const float* vbase = kbase + NKV * DH;

  bf8 qf[2][4];
#pragma unroll
  for (int mt = 0; mt < 2; ++mt)
#pragma unroll
    for (int kc = 0; kc < 4; ++kc) {
      int row = q0 + mrow0 + mt * 16 + l15;
      int d0  = kc * 32 + quad * 8;
      const float* src = q + ((size_t)(b * SQ + row) * NH + head) * DH + d0;
      f4 a = *(const f4*)src;
      f4 c = *(const f4*)(src + 4);
      qf[mt][kc] = pack8s(a, c, SCALE_LOG2E);
    }

  f4 O[2][8];
  float mrow[2][4], lrow[2][4];
#pragma unroll
  for (int mt = 0; mt < 2; ++mt) {
#pragma unroll
    for (int nt = 0; nt < 8; ++nt) O[mt][nt] = (f4){0.f, 0.f, 0.f, 0.f};
#pragma unroll
    for (int r = 0; r < 4; ++r) { mrow[mt][r] = -1e30f; lrow[mt][r] = 0.f; }
  }

  for (int kt = 0; kt <= qt; ++kt) {
    if (kt) __syncthreads();
    const int k0 = kt * 64;
#pragma unroll
    for (int i = 0; i < 4; ++i) {
      int id  = i * 256 + tid;
      int key = id >> 4;
      int c   = id & 15;
      const float* src = kbase + (size_t)(k0 + key) * KVSTRIDE + c * 8;
      f4 a = *(const f4*)src;
      f4 bb = *(const f4*)(src + 4);
      *(bf8*)&lsK[(key * 16 + (c ^ (key & 7))) * 8] = pack8(a, bb);
    }
#pragma unroll
    for (int i = 0; i < 4; ++i) {
      int u  = i * 4 + w;
      int kg = u >> 1;
      int d  = (u & 1) * 64 + l;
      const float* src = vbase + (size_t)(k0 + kg * 8) * KVSTRIDE + d;
      bf8 v;
#pragma unroll
      for (int kk = 0; kk < 8; ++kk) v[kk] = f2bf(src[(size_t)kk * KVSTRIDE]);
      *(bf8*)&lsV[(d * 8 + (kg ^ (d & 7))) * 8] = v;
    }
    __syncthreads();

    f4 S[2][4];
#pragma unroll
    for (int mt = 0; mt < 2; ++mt)
#pragma unroll
      for (int nt = 0; nt < 4; ++nt) S[mt][nt] = (f4){0.f, 0.f, 0.f, 0.f};
#pragma unroll
    for (int kc = 0; kc < 4; ++kc)
#pragma unroll
      for (int nt = 0; nt < 4; ++nt) {
        int key = nt * 16 + l15;
        int c   = kc * 4 + quad;
        bf8 kf = *(const bf8*)&lsK[(key * 16 + (c ^ (key & 7))) * 8];
        S[0][nt] = __builtin_amdgcn_mfma_f32_16x16x32_bf16(qf[0][kc], kf, S[0][nt], 0, 0, 0);
        S[1][nt] = __builtin_amdgcn_mfma_f32_16x16x32_bf16(qf[1][kc], kf, S[1][nt], 0, 0, 0);
      }

    if (kt == qt) {
#pragma unroll
      for (int mt = 0; mt < 2; ++mt)
#pragma unroll
        for (int nt = 0; nt < 4; ++nt)
#pragma unroll
          for (int r = 0; r < 4; ++r) {
            int rloc = mrow0 + mt * 16 + quad * 4 + r;
            int kloc = nt * 16 + l15;
            if (kloc > rloc) S[mt][nt][r] = -1e30f;
          }
    }

#pragma unroll
    for (int mt = 0; mt < 2; ++mt)
#pragma unroll
      for (int r = 0; r < 4; ++r) {
        float mx = fmaxf(fmaxf(S[mt][0][r], S[mt][1][r]),
                         fmaxf(S[mt][2][r], S[mt][3][r]));
        mx = rowmax16(mx);
        float mold = mrow[mt][r];
        float mnew = fmaxf(mold, mx);
        float alpha = fast_exp2(mold - mnew);
        mrow[mt][r] = mnew;
        float rs = 0.f;
#pragma unroll
        for (int nt = 0; nt < 4; ++nt) {
          float pe = fast_exp2(S[mt][nt][r] - mnew);
          S[mt][nt][r] = pe;
          rs += pe;
        }
        rs = rowsum16(rs);
        lrow[mt][r] = lrow[mt][r] * alpha + rs;
#pragma unroll
        for (int nt = 0; nt < 8; ++nt) O[mt][nt][r] *= alpha;
        int m = mt * 16 + quad * 4 + r;
#pragma unroll
        for (int nt = 0; nt < 4; ++nt) {
          int key = nt * 16 + l15;
          lsP[w][(m * 8 + ((key >> 3) ^ (m & 7))) * 8 + (key & 7)] =
              f2bf(S[mt][nt][r]);
        }
      }

#pragma unroll
    for (int kc = 0; kc < 2; ++kc) {
      bf8 pf[2];
#pragma unroll
      for (int mt = 0; mt < 2; ++mt) {
        int m = mt * 16 + l15;
        int c = kc * 4 + quad;
        pf[mt] = *(const bf8*)&lsP[w][(m * 8 + (c ^ (m & 7))) * 8];
      }
#pragma unroll
      for (int nt = 0; nt < 8; ++nt) {
        int d = nt * 16 + l15;
        int c = kc * 4 + quad;
        bf8 vf = *(const bf8*)&lsV[(d * 8 + (c ^ (d & 7))) * 8];
        O[0][nt] = __builtin_amdgcn_mfma_f32_16x16x32_bf16(pf[0], vf, O[0][nt], 0, 0, 0);
        O[1][nt] = __builtin_amdgcn_mfma_f32_16x16x32_bf16(pf[1], vf, O[1][nt], 0, 0, 0);
      }
    }
  }

#pragma unroll
  for (int mt = 0; mt < 2; ++mt)
#pragma unroll
    for (int r = 0; r < 4; ++r) {
      float linv = 1.0f / lrow[mt][r];
      int row = q0 + mrow0 + mt * 16 + quad * 4 + r;
      float* dst = out + ((size_t)(b * SQ + row) * NH + head) * DH + l15;
#pragma unroll
      for (int nt = 0; nt < 8; ++nt) dst[nt * 16] = O[mt][nt][r] * linv;
    }
}

extern "C" void kernel_launch(void* const* d_in, const int* in_sizes, int n_in,
                              void* d_out, int out_size, void* d_ws, size_t ws_size,
                              hipStream_t stream) {
  const float* q  = (const float*)d_in[0];
  const float* kv = (const float*)d_in[1];
  float* out      = (float*)d_out;
  (void)in_sizes; (void)n_in; (void)out_size;

  const size_t kb_elems = (size_t)2 * 8 * 32 * 8192;          // 4,194,304 shorts
  const size_t need = 2 * kb_elems * sizeof(short);            // 16 MB

  if (ws_size >= need) {
    short* Kb = (short*)d_ws;
    short* Vb = Kb + kb_elems;
    conv_kv<<<dim3(2048, 2), 256, 0, stream>>>(kv, Kb, Vb);
    fa_fwd12<<<dim3(256), dim3(512), 0, stream>>>(q, Kb, Vb, out);
  } else {
    fa_fwd_v1<<<dim3(512), dim3(256), 0, stream>>>(q, kv, out);
  }
}